// Round 4
// baseline (3154.428 us; speedup 1.0000x reference)
//
#include <hip/hip_runtime.h>
#include <hip/hip_bf16.h>

#define HW 64
#define L4 4096
#define CC 56
#define DI 112
#define DSN 16
#define NBLK 10

typedef const float* BP;

__device__ __forceinline__ float bf(BP p, int i) { return p[i]; }
__device__ __forceinline__ float siluf(float x) { return x / (1.f + __expf(-x)); }
__device__ __forceinline__ float geluf(float x) { return 0.5f * x * (1.f + erff(x * 0.70710678f)); }
__device__ __forceinline__ float softplusf(float x) { return fmaxf(x, 0.f) + log1pf(__expf(-fabsf(x))); }

// ---- stem: pointwise 3->56 ----
__global__ void k_fea_pw(BP x, BP w, float* __restrict__ t0) {
    int tid = blockIdx.x * blockDim.x + threadIdx.x;
    if (tid >= CC * L4) return;
    int c = tid >> 12, l = tid & 4095;
    float acc = 0.f;
    for (int i = 0; i < 3; ++i) acc += bf(x, i * L4 + l) * bf(w, c * 3 + i);
    t0[tid] = acc;
}

// ---- generic depthwise 3x3, optional silu, optional residual add ----
__global__ void k_dw3x3(const float* __restrict__ src, BP w, BP bvec, float* __restrict__ dst,
                        int nch, int S, int act, const float* __restrict__ addsrc) {
    int tid = blockIdx.x * blockDim.x + threadIdx.x;
    int tot = nch * S * S;
    if (tid >= tot) return;
    int c = tid / (S * S); int rem = tid - c * (S * S);
    int y = rem / S, x = rem - y * S;
    float acc = bvec ? bf(bvec, c) : 0.f;
    const float* sc = src + c * S * S;
    BP wr = w + c * 9;
    for (int ky = 0; ky < 3; ++ky) {
        int yy = y + ky - 1; if (yy < 0 || yy >= S) continue;
        for (int kx = 0; kx < 3; ++kx) {
            int xx = x + kx - 1; if (xx < 0 || xx >= S) continue;
            acc += sc[yy * S + xx] * bf(wr, ky * 3 + kx);
        }
    }
    if (act == 1) acc = siluf(acc);
    if (addsrc) acc += addsrc[tid];
    dst[tid] = acc;
}

// ---- per-pixel layernorm over channels ([c][l] layout), optional gelu ----
__global__ void k_ln_pix(const float* __restrict__ src, BP w, BP b, float* __restrict__ dst,
                         int nch, float eps, int gelu_after) {
    int l = blockIdx.x * blockDim.x + threadIdx.x;
    if (l >= L4) return;
    float s = 0.f, s2 = 0.f;
    for (int c = 0; c < nch; ++c) { float v = src[c * L4 + l]; s += v; s2 += v * v; }
    float mu = s / nch;
    float var = fmaxf(s2 / nch - mu * mu, 0.f);
    float rstd = rsqrtf(var + eps);
    for (int c = 0; c < nch; ++c) {
        float v = (src[c * L4 + l] - mu) * rstd * bf(w, c) + bf(b, c);
        if (gelu_after) v = geluf(v);
        dst[c * L4 + l] = v;
    }
}

// ---- LDS-tiled channel GEMM: out[j][l] = bias[j] + sum_i src[i][l]*w[j*nin+i] (+addsrc)
// grid = (64 l-tiles, ceil(nout/32) j-tiles); block = 256 = 64 lanes x 4 jg; 8 j per thread.
// out_mode 0: dst[j*L4+l]; out_mode 1 (xproj): dst[((j/36)*L4+l)*36 + j%36]
__global__ void __launch_bounds__(256) k_gemm(
        const float* __restrict__ src, BP w, BP bvec, const float* __restrict__ addsrc,
        float* __restrict__ dst, int nin, int nout, int out_mode) {
    int lane = threadIdx.x & 63;
    int jg = threadIdx.x >> 6;
    int l = blockIdx.x * 64 + lane;
    int j0 = blockIdx.y * 32;
    __shared__ float sw[32 * 56];
    float acc[8];
    #pragma unroll
    for (int jj = 0; jj < 8; ++jj) acc[jj] = 0.f;

    for (int i0 = 0; i0 < nin; i0 += 56) {
        int kc = nin - i0; if (kc > 56) kc = 56;
        __syncthreads();
        for (int idx = threadIdx.x; idx < 32 * 56; idx += 256) {
            int jj = idx / 56, ii = idx % 56;
            int j = j0 + jj;
            sw[idx] = (j < nout && ii < kc) ? w[(size_t)j * nin + i0 + ii] : 0.f;
        }
        __syncthreads();
        for (int ii = 0; ii < kc; ++ii) {
            float s = src[(size_t)(i0 + ii) * L4 + l];
            #pragma unroll
            for (int jj = 0; jj < 8; ++jj)
                acc[jj] += s * sw[(jg * 8 + jj) * 56 + ii];
        }
    }
    #pragma unroll
    for (int jj = 0; jj < 8; ++jj) {
        int j = j0 + jg * 8 + jj;
        if (j >= nout) continue;
        float v = acc[jj];
        if (bvec) v += bf(bvec, j);
        if (out_mode == 0) {
            size_t idx = (size_t)j * L4 + l;
            if (addsrc) v += addsrc[idx];
            dst[idx] = v;
        } else {
            int k = j / 36, c = j - k * 36;
            dst[((size_t)k * L4 + l) * 36 + c] = v;
        }
    }
}

// ---- delta: delta[(k*112+d)*4096+l] = softplus(sum_r pk[k][l][r]*dtw + dtb) ----
__global__ void k_delta(const float* __restrict__ pk, BP dtw, BP dtb, float* __restrict__ delta) {
    int tid = blockIdx.x * blockDim.x + threadIdx.x;
    if (tid >= 4 * DI * L4) return;
    int l = tid & 4095; int kd = tid >> 12; int d = kd % DI; int k = kd / DI;
    const float* pp = pk + ((size_t)k * L4 + l) * 36;
    BP wr = dtw + (k * DI + d) * 4;
    float acc = bf(dtb, k * DI + d);
    for (int r = 0; r < 4; ++r) acc += pp[r] * bf(wr, r);
    delta[tid] = softplusf(acc);
}

// ---- chunked selective scan: one block per (k,d) pair; 64 chunks x 16 states ----
__global__ void __launch_bounds__(1024) k_scan(
        const float* __restrict__ delta, const float* __restrict__ xc,
        const float* __restrict__ pk, BP Alog, float* __restrict__ ybuf) {
    int pair = blockIdx.x;           // k*112+d
    int n = threadIdx.x & 15;        // state index
    int c = threadIdx.x >> 4;        // chunk index, 0..63
    int k = pair / DI, d = pair - k * DI;
    float a = -__expf(bf(Alog, pair * DSN + n));
    const float* dptr = delta + (size_t)pair * L4;
    const float* xptr = xc + (size_t)d * L4;
    const float* pkk = pk + (size_t)k * L4 * 36;
    float* yptr = ybuf + (size_t)pair * L4;

    __shared__ float sP[64 * 16];
    __shared__ float sHe[64 * 16];
    __shared__ float sCar[64 * 16];

    float h = 0.f, P = 1.f;
    int t0 = c * 64;
    for (int j = 0; j < 64; ++j) {
        int t = t0 + j;
        int tt = (k >= 2) ? (4095 - t) : t;
        int p = (k & 1) ? (((tt & 63) << 6) | (tt >> 6)) : tt;
        float dl = dptr[p];
        float xl = xptr[p];
        float Bn = pkk[p * 36 + 4 + n];
        float e = __expf(dl * a);
        h = e * h + dl * xl * Bn;
        P *= e;
    }
    sP[c * 16 + n] = P;
    sHe[c * 16 + n] = h;
    __syncthreads();

    if (threadIdx.x < 16) {
        float H = 0.f;
        for (int cc = 0; cc < 64; ++cc) {
            sCar[cc * 16 + n] = H;
            H = sP[cc * 16 + n] * H + sHe[cc * 16 + n];
        }
    }
    __syncthreads();

    h = sCar[c * 16 + n];
    for (int j = 0; j < 64; ++j) {
        int t = t0 + j;
        int tt = (k >= 2) ? (4095 - t) : t;
        int p = (k & 1) ? (((tt & 63) << 6) | (tt >> 6)) : tt;
        float dl = dptr[p];
        float xl = xptr[p];
        float Bn = pkk[p * 36 + 4 + n];
        float Cn = pkk[p * 36 + 20 + n];
        float e = __expf(dl * a);
        h = e * h + dl * xl * Bn;
        float y = h * Cn;
        y += __shfl_xor(y, 1, 16);
        y += __shfl_xor(y, 2, 16);
        y += __shfl_xor(y, 4, 16);
        y += __shfl_xor(y, 8, 16);
        if (n == 0) yptr[p] = y;
    }
}

// ---- combine 4 directions + D*x, LN(112, eps 1e-5, onorm), gate with silu(z) ----
__global__ void k_combine(const float* __restrict__ ybuf, const float* __restrict__ xc,
                          const float* __restrict__ zbuf, BP Dp, BP ow, BP ob,
                          float* __restrict__ gbuf) {
    int l = blockIdx.x * blockDim.x + threadIdx.x;
    if (l >= L4) return;
    float s = 0.f, s2 = 0.f;
    for (int d = 0; d < DI; ++d) {
        float Ds = bf(Dp, d) + bf(Dp, DI + d) + bf(Dp, 2 * DI + d) + bf(Dp, 3 * DI + d);
        float yv = ybuf[d * L4 + l] + ybuf[(DI + d) * L4 + l] + ybuf[(2 * DI + d) * L4 + l]
                 + ybuf[(3 * DI + d) * L4 + l] + Ds * xc[d * L4 + l];
        gbuf[d * L4 + l] = yv; s += yv; s2 += yv * yv;
    }
    float mu = s / DI;
    float var = fmaxf(s2 / DI - mu * mu, 0.f);
    float rstd = rsqrtf(var + 1e-5f);
    for (int d = 0; d < DI; ++d) {
        float v = (gbuf[d * L4 + l] - mu) * rstd * bf(ow, d) + bf(ob, d);
        gbuf[d * L4 + l] = v * siluf(zbuf[d * L4 + l]);
    }
}

// ---- SAFM pools (scales 2,4,8) ----
__global__ void k_pools(const float* __restrict__ xln, float* __restrict__ p1,
                        float* __restrict__ p2, float* __restrict__ p3) {
    int tid = blockIdx.x * blockDim.x + threadIdx.x;
    int f, S, idx, chbase; float* dst;
    if (tid < 14336)      { f = 2; S = 32; idx = tid;          chbase = 14; dst = p1; }
    else if (tid < 17920) { f = 4; S = 16; idx = tid - 14336;  chbase = 28; dst = p2; }
    else if (tid < 18816) { f = 8; S = 8;  idx = tid - 17920;  chbase = 42; dst = p3; }
    else return;
    int c = idx / (S * S); int rem = idx - c * S * S; int y = rem / S, x = rem - y * S;
    float m = -3.4e38f;
    for (int dy = 0; dy < f; ++dy)
        for (int dx = 0; dx < f; ++dx) {
            float v = xln[(chbase + c) * L4 + (y * f + dy) * HW + (x * f + dx)];
            m = fmaxf(m, v);
        }
    dst[idx] = m;
}

// ---- SAFM depthwise convs at 4 scales (fused) ----
__global__ void k_mfr(const float* __restrict__ xln, const float* __restrict__ p1,
                      const float* __restrict__ p2, const float* __restrict__ p3,
                      BP mw, BP mb, float* __restrict__ s0, float* __restrict__ s1,
                      float* __restrict__ s2, float* __restrict__ s3) {
    int tid = blockIdx.x * blockDim.x + threadIdx.x;
    int S, i, idx; const float* src; float* dst;
    if (tid < 57344)      { S = 64; i = 0; idx = tid;          src = xln; dst = s0; }
    else if (tid < 71680) { S = 32; i = 1; idx = tid - 57344;  src = p1;  dst = s1; }
    else if (tid < 75264) { S = 16; i = 2; idx = tid - 71680;  src = p2;  dst = s2; }
    else if (tid < 76160) { S = 8;  i = 3; idx = tid - 75264;  src = p3;  dst = s3; }
    else return;
    int c = idx / (S * S); int rem = idx - c * S * S; int y = rem / S, x = rem - y * S;
    int srcstride = (i == 0) ? L4 : S * S;
    float acc = bf(mb, i * 14 + c);
    BP wr = mw + (i * 14 + c) * 9;
    const float* sc = src + c * srcstride;
    for (int ky = 0; ky < 3; ++ky) {
        int yy = y + ky - 1; if (yy < 0 || yy >= S) continue;
        for (int kx = 0; kx < 3; ++kx) {
            int xx = x + kx - 1; if (xx < 0 || xx >= S) continue;
            acc += sc[yy * S + xx] * bf(wr, ky * 3 + kx);
        }
    }
    dst[idx] = acc;
}

// ---- SAFM aggregate 1x1 + gelu gate + residual, writes trunk slice ----
__global__ void k_aggr(const float* __restrict__ s0, const float* __restrict__ s1,
                       const float* __restrict__ s2, const float* __restrict__ s3,
                       const float* __restrict__ xln, const float* __restrict__ x_mid,
                       BP aw, BP ab, float* __restrict__ out) {
    int tid = blockIdx.x * blockDim.x + threadIdx.x;
    if (tid >= CC * L4) return;
    int c = tid >> 12, l = tid & 4095;
    int h = l >> 6, w = l & 63;
    int o1 = (h >> 1) * 32 + (w >> 1);
    int o2 = (h >> 2) * 16 + (w >> 2);
    int o3 = (h >> 3) * 8 + (w >> 3);
    float acc = bf(ab, c);
    BP wr = aw + c * 56;
    for (int cg = 0; cg < 14; ++cg) acc += s0[cg * 4096 + l]  * bf(wr, cg);
    for (int cg = 0; cg < 14; ++cg) acc += s1[cg * 1024 + o1] * bf(wr, 14 + cg);
    for (int cg = 0; cg < 14; ++cg) acc += s2[cg * 256 + o2]  * bf(wr, 28 + cg);
    for (int cg = 0; cg < 14; ++cg) acc += s3[cg * 64 + o3]   * bf(wr, 42 + cg);
    out[tid] = x_mid[tid] + geluf(acc) * xln[tid];
}

// ---- up conv 3x3 (56->27) + pixel shuffle x3, fp32 output ----
__global__ void k_up(const float* __restrict__ out_lr, BP uw, BP ub, float* __restrict__ out) {
    int tid = blockIdx.x * blockDim.x + threadIdx.x;
    if (tid >= 27 * L4) return;
    int o = tid >> 12, l = tid & 4095;
    int h = l >> 6, w = l & 63;
    float acc = bf(ub, o);
    for (int c = 0; c < CC; ++c) {
        const float* sc = out_lr + c * L4;
        BP wr = uw + (o * CC + c) * 9;
        for (int ky = 0; ky < 3; ++ky) {
            int yy = h + ky - 1; if (yy < 0 || yy >= HW) continue;
            for (int kx = 0; kx < 3; ++kx) {
                int xx = w + kx - 1; if (xx < 0 || xx >= HW) continue;
                acc += sc[yy * HW + xx] * bf(wr, ky * 3 + kx);
            }
        }
    }
    int ch = o / 9; int rr = (o % 9) / 3; int ss = o % 3;
    out[ch * (192 * 192) + (h * 3 + rr) * 192 + (w * 3 + ss)] = acc;
}

extern "C" void kernel_launch(void* const* d_in, const int* in_sizes, int n_in,
                              void* d_out, int out_size, void* d_ws, size_t ws_size,
                              hipStream_t stream) {
    BP in0  = (BP)d_in[0];
    BP in1  = (BP)d_in[1];
    BP in2  = (BP)d_in[2];
    BP in3  = (BP)d_in[3];
    BP in4  = (BP)d_in[4];
    BP in5  = (BP)d_in[5];
    BP in6  = (BP)d_in[6];
    BP in7  = (BP)d_in[7];
    BP in8  = (BP)d_in[8];
    BP in9  = (BP)d_in[9];
    BP in10 = (BP)d_in[10];
    BP in11 = (BP)d_in[11];
    BP in12 = (BP)d_in[12];
    BP in13 = (BP)d_in[13];
    BP in14 = (BP)d_in[14];
    BP in15 = (BP)d_in[15];
    BP in16 = (BP)d_in[16];
    BP in17 = (BP)d_in[17];
    BP in18 = (BP)d_in[18];
    BP in19 = (BP)d_in[19];
    BP in20 = (BP)d_in[20];
    BP in21 = (BP)d_in[21];
    BP in22 = (BP)d_in[22];
    BP in23 = (BP)d_in[23];
    BP in24 = (BP)d_in[24];
    BP in25 = (BP)d_in[25];
    BP in26 = (BP)d_in[26];
    BP in27 = (BP)d_in[27];
    BP in28 = (BP)d_in[28];
    BP in29 = (BP)d_in[29];
    BP in30 = (BP)d_in[30];
    BP in31 = (BP)d_in[31];

    float* ws = (float*)d_ws;
    float* trunk   = ws; ws += 560 * L4;
    float* out_fea = ws; ws += CC * L4;
    float* t0      = ws; ws += CC * L4;
    float* xz      = ws; ws += 224 * L4;
    float* xc      = ws; ws += DI * L4;
    float* pk      = ws; ws += 4 * 36 * L4;
    float* delta   = ws; ws += 4 * DI * L4;
    float* ybuf    = ws; ws += 4 * DI * L4;
    float* gbuf    = ws; ws += DI * L4;
    float* ln1buf  = ws; ws += CC * L4;
    float* x_mid   = ws; ws += CC * L4;
    float* xln     = ws; ws += CC * L4;
    float* p1      = ws; ws += 14 * 1024;
    float* p2      = ws; ws += 14 * 256;
    float* p3      = ws; ws += 14 * 64;
    float* s0      = ws; ws += 14 * 4096;
    float* s1      = ws; ws += 14 * 1024;
    float* s2      = ws; ws += 14 * 256;
    float* s3      = ws; ws += 14 * 64;
    float* bufB    = ws; ws += CC * L4;
    float* gB      = ws; ws += CC * L4;
    float* tbuf    = ws; ws += CC * L4;
    float* out_lr  = ws; ws += CC * L4;

    auto nb256 = [](int n) { return dim3((n + 255) / 256); };
    auto gemm_grid = [](int nout) { return dim3(64, (nout + 31) / 32); };

    // stem
    k_fea_pw<<<nb256(CC * L4), 256, 0, stream>>>(in0, in1, t0);
    k_dw3x3<<<nb256(CC * L4), 256, 0, stream>>>(t0, in2, in3, out_fea, CC, HW, 0, nullptr);

    for (int nb = 0; nb < NBLK; ++nb) {
        const float* xin = (nb == 0) ? out_fea : trunk + (size_t)(nb - 1) * CC * L4;
        float* xout = trunk + (size_t)nb * CC * L4;
        BP ln1w = in4 + nb * 56,        ln1b = in5 + nb * 56;
        BP ipw  = in6 + nb * 224 * 56;
        BP cw   = in7 + nb * 112 * 9,   cb   = in8 + nb * 112;
        BP xpw  = in9 + nb * 4 * 36 * 112;
        BP dtw  = in10 + nb * 4 * 112 * 4, dtb = in11 + nb * 448;
        BP alog = in12 + nb * 448 * 16, Dp   = in13 + nb * 448;
        BP onw  = in14 + nb * 112,      onb  = in15 + nb * 112;
        BP opw  = in16 + nb * 56 * 112;
        BP nw   = in17 + nb * 56,       nbv  = in18 + nb * 56;
        BP mw   = in19 + nb * 4 * 14 * 9, mb = in20 + nb * 56;
        BP aw   = in21 + nb * 56 * 56,  ab   = in22 + nb * 56;

        k_ln_pix<<<nb256(L4), 256, 0, stream>>>(xin, ln1w, ln1b, ln1buf, CC, 1e-5f, 0);
        k_gemm<<<gemm_grid(224), 256, 0, stream>>>(ln1buf, ipw, nullptr, nullptr, xz, 56, 224, 0);
        k_dw3x3<<<nb256(DI * L4), 256, 0, stream>>>(xz, cw, cb, xc, DI, HW, 1, nullptr);
        k_gemm<<<gemm_grid(144), 256, 0, stream>>>(xc, xpw, nullptr, nullptr, pk, 112, 144, 1);
        k_delta<<<nb256(4 * DI * L4), 256, 0, stream>>>(pk, dtw, dtb, delta);
        k_scan<<<dim3(4 * DI), 1024, 0, stream>>>(delta, xc, pk, alog, ybuf);
        k_combine<<<nb256(L4), 256, 0, stream>>>(ybuf, xc, xz + 112 * L4, Dp, onw, onb, gbuf);
        k_gemm<<<gemm_grid(56), 256, 0, stream>>>(gbuf, opw, nullptr, xin, x_mid, 112, 56, 0);
        k_ln_pix<<<nb256(L4), 256, 0, stream>>>(x_mid, nw, nbv, xln, CC, 1e-6f, 0);
        k_pools<<<nb256(18816), 256, 0, stream>>>(xln, p1, p2, p3);
        k_mfr<<<nb256(76160), 256, 0, stream>>>(xln, p1, p2, p3, mw, mb, s0, s1, s2, s3);
        k_aggr<<<nb256(CC * L4), 256, 0, stream>>>(s0, s1, s2, s3, xln, x_mid, aw, ab, xout);
    }

    // tail
    k_gemm<<<gemm_grid(56), 256, 0, stream>>>(trunk, in23, in24, nullptr, bufB, 560, 56, 0);
    k_ln_pix<<<nb256(L4), 256, 0, stream>>>(bufB, in25, in26, gB, CC, 1e-6f, 1);
    k_gemm<<<gemm_grid(56), 256, 0, stream>>>(gB, in27, nullptr, nullptr, tbuf, 56, 56, 0);
    k_dw3x3<<<nb256(CC * L4), 256, 0, stream>>>(tbuf, in28, in29, out_lr, CC, HW, 0, out_fea);
    k_up<<<nb256(27 * L4), 256, 0, stream>>>(out_lr, in30, in31, (float*)d_out);
}

// Round 5
// 2445.404 us; speedup vs baseline: 1.2899x; 1.2899x over previous
//
#include <hip/hip_runtime.h>
#include <hip/hip_bf16.h>

#define HW 64
#define L4 4096
#define CC 56
#define DI 112
#define DSN 16
#define NBLK 10

typedef const float* BP;

__device__ __forceinline__ float bf(BP p, int i) { return p[i]; }
__device__ __forceinline__ float siluf(float x) { return x / (1.f + __expf(-x)); }
__device__ __forceinline__ float geluf(float x) { return 0.5f * x * (1.f + erff(x * 0.70710678f)); }
__device__ __forceinline__ float softplusf(float x) { return fmaxf(x, 0.f) + log1pf(__expf(-fabsf(x))); }

// ---- stem: pointwise 3->56 ----
__global__ void k_fea_pw(BP x, BP w, float* __restrict__ t0) {
    int tid = blockIdx.x * blockDim.x + threadIdx.x;
    if (tid >= CC * L4) return;
    int c = tid >> 12, l = tid & 4095;
    float acc = 0.f;
    for (int i = 0; i < 3; ++i) acc += bf(x, i * L4 + l) * bf(w, c * 3 + i);
    t0[tid] = acc;
}

// ---- generic depthwise 3x3, optional silu, optional residual add ----
__global__ void k_dw3x3(const float* __restrict__ src, BP w, BP bvec, float* __restrict__ dst,
                        int nch, int S, int act, const float* __restrict__ addsrc) {
    int tid = blockIdx.x * blockDim.x + threadIdx.x;
    int tot = nch * S * S;
    if (tid >= tot) return;
    int c = tid / (S * S); int rem = tid - c * (S * S);
    int y = rem / S, x = rem - y * S;
    float acc = bvec ? bf(bvec, c) : 0.f;
    const float* sc = src + c * S * S;
    BP wr = w + c * 9;
    for (int ky = 0; ky < 3; ++ky) {
        int yy = y + ky - 1; if (yy < 0 || yy >= S) continue;
        for (int kx = 0; kx < 3; ++kx) {
            int xx = x + kx - 1; if (xx < 0 || xx >= S) continue;
            acc += sc[yy * S + xx] * bf(wr, ky * 3 + kx);
        }
    }
    if (act == 1) acc = siluf(acc);
    if (addsrc) acc += addsrc[tid];
    dst[tid] = acc;
}

// ---- per-pixel layernorm over channels ([c][l] layout), optional gelu ----
__global__ void k_ln_pix(const float* __restrict__ src, BP w, BP b, float* __restrict__ dst,
                         int nch, float eps, int gelu_after) {
    int l = blockIdx.x * blockDim.x + threadIdx.x;
    if (l >= L4) return;
    float s = 0.f, s2 = 0.f;
    for (int c = 0; c < nch; ++c) { float v = src[c * L4 + l]; s += v; s2 += v * v; }
    float mu = s / nch;
    float var = fmaxf(s2 / nch - mu * mu, 0.f);
    float rstd = rsqrtf(var + eps);
    for (int c = 0; c < nch; ++c) {
        float v = (src[c * L4 + l] - mu) * rstd * bf(w, c) + bf(b, c);
        if (gelu_after) v = geluf(v);
        dst[c * L4 + l] = v;
    }
}

// ---- LDS-staged channel GEMM (both operands in LDS; K-loop global-load-free)
// tile: 64 pixels x 16 outputs; block 256 = 64 lanes x 4 jg; 4 outputs/thread.
// requires nin % 56 == 0. grid = (64, ceil(nout/16)).
// out_mode 0: dst[j*L4+l] (+addsrc); out_mode 1 (xproj): dst[((j/36)*L4+l)*36 + j%36]
__global__ void __launch_bounds__(256) k_gemm(
        const float* __restrict__ src, BP w, BP bvec, const float* __restrict__ addsrc,
        float* __restrict__ dst, int nin, int nout, int out_mode) {
    int lane = threadIdx.x & 63;
    int jg = threadIdx.x >> 6;
    int l0 = blockIdx.x * 64;
    int j0 = blockIdx.y * 16;
    __shared__ __align__(16) float sS[56 * 64];
    __shared__ __align__(16) float sw[16 * 56];
    float acc[4] = {0.f, 0.f, 0.f, 0.f};

    for (int i0 = 0; i0 < nin; i0 += 56) {
        __syncthreads();
        // stage src tile: sS[ii][px]
        for (int idx = threadIdx.x; idx < 56 * 64; idx += 256) {
            int ii = idx >> 6, px = idx & 63;
            sS[idx] = src[(size_t)(i0 + ii) * L4 + l0 + px];
        }
        // stage weights: sw[jj][ii], zero-pad beyond nout
        for (int idx = threadIdx.x; idx < 16 * 56; idx += 256) {
            int jj = idx / 56, ii = idx - jj * 56;
            int j = j0 + jj;
            sw[idx] = (j < nout) ? w[(size_t)j * nin + i0 + ii] : 0.f;
        }
        __syncthreads();
        #pragma unroll
        for (int ii = 0; ii < 56; ii += 4) {
            float s0 = sS[(ii + 0) * 64 + lane];
            float s1 = sS[(ii + 1) * 64 + lane];
            float s2 = sS[(ii + 2) * 64 + lane];
            float s3 = sS[(ii + 3) * 64 + lane];
            #pragma unroll
            for (int jj = 0; jj < 4; ++jj) {
                const float4 wv = *(const float4*)&sw[(jg * 4 + jj) * 56 + ii];
                acc[jj] += s0 * wv.x + s1 * wv.y + s2 * wv.z + s3 * wv.w;
            }
        }
    }
    int l = l0 + lane;
    #pragma unroll
    for (int jj = 0; jj < 4; ++jj) {
        int j = j0 + jg * 4 + jj;
        if (j >= nout) continue;
        float v = acc[jj];
        if (bvec) v += bf(bvec, j);
        if (out_mode == 0) {
            size_t idx = (size_t)j * L4 + l;
            if (addsrc) v += addsrc[idx];
            dst[idx] = v;
        } else {
            int k = j / 36, c = j - k * 36;
            dst[((size_t)k * L4 + l) * 36 + c] = v;
        }
    }
}

// ---- delta: delta[(k*112+d)*4096+l] = softplus(sum_r pk[k][l][r]*dtw + dtb) ----
__global__ void k_delta(const float* __restrict__ pk, BP dtw, BP dtb, float* __restrict__ delta) {
    int tid = blockIdx.x * blockDim.x + threadIdx.x;
    if (tid >= 4 * DI * L4) return;
    int l = tid & 4095; int kd = tid >> 12; int d = kd % DI; int k = kd / DI;
    const float* pp = pk + ((size_t)k * L4 + l) * 36;
    BP wr = dtw + (k * DI + d) * 4;
    float acc = bf(dtb, k * DI + d);
    for (int r = 0; r < 4; ++r) acc += pp[r] * bf(wr, r);
    delta[tid] = softplusf(acc);
}

// ---- chunked selective scan: one block per (k,d) pair; 64 chunks x 16 states ----
__global__ void __launch_bounds__(1024) k_scan(
        const float* __restrict__ delta, const float* __restrict__ xc,
        const float* __restrict__ pk, BP Alog, float* __restrict__ ybuf) {
    int pair = blockIdx.x;           // k*112+d
    int n = threadIdx.x & 15;        // state index
    int c = threadIdx.x >> 4;        // chunk index, 0..63
    int k = pair / DI, d = pair - k * DI;
    float a = -__expf(bf(Alog, pair * DSN + n));
    const float* dptr = delta + (size_t)pair * L4;
    const float* xptr = xc + (size_t)d * L4;
    const float* pkk = pk + (size_t)k * L4 * 36;
    float* yptr = ybuf + (size_t)pair * L4;

    __shared__ float sP[64 * 16];
    __shared__ float sHe[64 * 16];
    __shared__ float sCar[64 * 16];

    float h = 0.f, P = 1.f;
    int t0 = c * 64;
    for (int j = 0; j < 64; ++j) {
        int t = t0 + j;
        int tt = (k >= 2) ? (4095 - t) : t;
        int p = (k & 1) ? (((tt & 63) << 6) | (tt >> 6)) : tt;
        float dl = dptr[p];
        float xl = xptr[p];
        float Bn = pkk[p * 36 + 4 + n];
        float e = __expf(dl * a);
        h = e * h + dl * xl * Bn;
        P *= e;
    }
    sP[c * 16 + n] = P;
    sHe[c * 16 + n] = h;
    __syncthreads();

    if (threadIdx.x < 16) {
        float H = 0.f;
        for (int cc = 0; cc < 64; ++cc) {
            sCar[cc * 16 + n] = H;
            H = sP[cc * 16 + n] * H + sHe[cc * 16 + n];
        }
    }
    __syncthreads();

    h = sCar[c * 16 + n];
    for (int j = 0; j < 64; ++j) {
        int t = t0 + j;
        int tt = (k >= 2) ? (4095 - t) : t;
        int p = (k & 1) ? (((tt & 63) << 6) | (tt >> 6)) : tt;
        float dl = dptr[p];
        float xl = xptr[p];
        float Bn = pkk[p * 36 + 4 + n];
        float Cn = pkk[p * 36 + 20 + n];
        float e = __expf(dl * a);
        h = e * h + dl * xl * Bn;
        float y = h * Cn;
        y += __shfl_xor(y, 1, 16);
        y += __shfl_xor(y, 2, 16);
        y += __shfl_xor(y, 4, 16);
        y += __shfl_xor(y, 8, 16);
        if (n == 0) yptr[p] = y;
    }
}

// ---- combine 4 directions + D*x, LN(112, eps 1e-5, onorm), gate with silu(z) ----
__global__ void k_combine(const float* __restrict__ ybuf, const float* __restrict__ xc,
                          const float* __restrict__ zbuf, BP Dp, BP ow, BP ob,
                          float* __restrict__ gbuf) {
    int l = blockIdx.x * blockDim.x + threadIdx.x;
    if (l >= L4) return;
    float s = 0.f, s2 = 0.f;
    for (int d = 0; d < DI; ++d) {
        float Ds = bf(Dp, d) + bf(Dp, DI + d) + bf(Dp, 2 * DI + d) + bf(Dp, 3 * DI + d);
        float yv = ybuf[d * L4 + l] + ybuf[(DI + d) * L4 + l] + ybuf[(2 * DI + d) * L4 + l]
                 + ybuf[(3 * DI + d) * L4 + l] + Ds * xc[d * L4 + l];
        gbuf[d * L4 + l] = yv; s += yv; s2 += yv * yv;
    }
    float mu = s / DI;
    float var = fmaxf(s2 / DI - mu * mu, 0.f);
    float rstd = rsqrtf(var + 1e-5f);
    for (int d = 0; d < DI; ++d) {
        float v = (gbuf[d * L4 + l] - mu) * rstd * bf(ow, d) + bf(ob, d);
        gbuf[d * L4 + l] = v * siluf(zbuf[d * L4 + l]);
    }
}

// ---- SAFM pools (scales 2,4,8) ----
__global__ void k_pools(const float* __restrict__ xln, float* __restrict__ p1,
                        float* __restrict__ p2, float* __restrict__ p3) {
    int tid = blockIdx.x * blockDim.x + threadIdx.x;
    int f, S, idx, chbase; float* dst;
    if (tid < 14336)      { f = 2; S = 32; idx = tid;          chbase = 14; dst = p1; }
    else if (tid < 17920) { f = 4; S = 16; idx = tid - 14336;  chbase = 28; dst = p2; }
    else if (tid < 18816) { f = 8; S = 8;  idx = tid - 17920;  chbase = 42; dst = p3; }
    else return;
    int c = idx / (S * S); int rem = idx - c * S * S; int y = rem / S, x = rem - y * S;
    float m = -3.4e38f;
    for (int dy = 0; dy < f; ++dy)
        for (int dx = 0; dx < f; ++dx) {
            float v = xln[(chbase + c) * L4 + (y * f + dy) * HW + (x * f + dx)];
            m = fmaxf(m, v);
        }
    dst[idx] = m;
}

// ---- SAFM depthwise convs at 4 scales (fused) ----
__global__ void k_mfr(const float* __restrict__ xln, const float* __restrict__ p1,
                      const float* __restrict__ p2, const float* __restrict__ p3,
                      BP mw, BP mb, float* __restrict__ s0, float* __restrict__ s1,
                      float* __restrict__ s2, float* __restrict__ s3) {
    int tid = blockIdx.x * blockDim.x + threadIdx.x;
    int S, i, idx; const float* src; float* dst;
    if (tid < 57344)      { S = 64; i = 0; idx = tid;          src = xln; dst = s0; }
    else if (tid < 71680) { S = 32; i = 1; idx = tid - 57344;  src = p1;  dst = s1; }
    else if (tid < 75264) { S = 16; i = 2; idx = tid - 71680;  src = p2;  dst = s2; }
    else if (tid < 76160) { S = 8;  i = 3; idx = tid - 75264;  src = p3;  dst = s3; }
    else return;
    int c = idx / (S * S); int rem = idx - c * S * S; int y = rem / S, x = rem - y * S;
    int srcstride = (i == 0) ? L4 : S * S;
    float acc = bf(mb, i * 14 + c);
    BP wr = mw + (i * 14 + c) * 9;
    const float* sc = src + c * srcstride;
    for (int ky = 0; ky < 3; ++ky) {
        int yy = y + ky - 1; if (yy < 0 || yy >= S) continue;
        for (int kx = 0; kx < 3; ++kx) {
            int xx = x + kx - 1; if (xx < 0 || xx >= S) continue;
            acc += sc[yy * S + xx] * bf(wr, ky * 3 + kx);
        }
    }
    dst[idx] = acc;
}

// ---- SAFM aggregate 1x1 + gelu gate + residual, writes trunk slice ----
__global__ void k_aggr(const float* __restrict__ s0, const float* __restrict__ s1,
                       const float* __restrict__ s2, const float* __restrict__ s3,
                       const float* __restrict__ xln, const float* __restrict__ x_mid,
                       BP aw, BP ab, float* __restrict__ out) {
    int tid = blockIdx.x * blockDim.x + threadIdx.x;
    if (tid >= CC * L4) return;
    int c = tid >> 12, l = tid & 4095;
    int h = l >> 6, w = l & 63;
    int o1 = (h >> 1) * 32 + (w >> 1);
    int o2 = (h >> 2) * 16 + (w >> 2);
    int o3 = (h >> 3) * 8 + (w >> 3);
    float acc = bf(ab, c);
    BP wr = aw + c * 56;
    for (int cg = 0; cg < 14; ++cg) acc += s0[cg * 4096 + l]  * bf(wr, cg);
    for (int cg = 0; cg < 14; ++cg) acc += s1[cg * 1024 + o1] * bf(wr, 14 + cg);
    for (int cg = 0; cg < 14; ++cg) acc += s2[cg * 256 + o2]  * bf(wr, 28 + cg);
    for (int cg = 0; cg < 14; ++cg) acc += s3[cg * 64 + o3]   * bf(wr, 42 + cg);
    out[tid] = x_mid[tid] + geluf(acc) * xln[tid];
}

// ---- up conv 3x3 (56->27) + pixel shuffle x3, fp32 output ----
__global__ void k_up(const float* __restrict__ out_lr, BP uw, BP ub, float* __restrict__ out) {
    int tid = blockIdx.x * blockDim.x + threadIdx.x;
    if (tid >= 27 * L4) return;
    int o = tid >> 12, l = tid & 4095;
    int h = l >> 6, w = l & 63;
    float acc = bf(ub, o);
    for (int c = 0; c < CC; ++c) {
        const float* sc = out_lr + c * L4;
        BP wr = uw + (o * CC + c) * 9;
        for (int ky = 0; ky < 3; ++ky) {
            int yy = h + ky - 1; if (yy < 0 || yy >= HW) continue;
            for (int kx = 0; kx < 3; ++kx) {
                int xx = w + kx - 1; if (xx < 0 || xx >= HW) continue;
                acc += sc[yy * HW + xx] * bf(wr, ky * 3 + kx);
            }
        }
    }
    int ch = o / 9; int rr = (o % 9) / 3; int ss = o % 3;
    out[ch * (192 * 192) + (h * 3 + rr) * 192 + (w * 3 + ss)] = acc;
}

extern "C" void kernel_launch(void* const* d_in, const int* in_sizes, int n_in,
                              void* d_out, int out_size, void* d_ws, size_t ws_size,
                              hipStream_t stream) {
    BP in0  = (BP)d_in[0];
    BP in1  = (BP)d_in[1];
    BP in2  = (BP)d_in[2];
    BP in3  = (BP)d_in[3];
    BP in4  = (BP)d_in[4];
    BP in5  = (BP)d_in[5];
    BP in6  = (BP)d_in[6];
    BP in7  = (BP)d_in[7];
    BP in8  = (BP)d_in[8];
    BP in9  = (BP)d_in[9];
    BP in10 = (BP)d_in[10];
    BP in11 = (BP)d_in[11];
    BP in12 = (BP)d_in[12];
    BP in13 = (BP)d_in[13];
    BP in14 = (BP)d_in[14];
    BP in15 = (BP)d_in[15];
    BP in16 = (BP)d_in[16];
    BP in17 = (BP)d_in[17];
    BP in18 = (BP)d_in[18];
    BP in19 = (BP)d_in[19];
    BP in20 = (BP)d_in[20];
    BP in21 = (BP)d_in[21];
    BP in22 = (BP)d_in[22];
    BP in23 = (BP)d_in[23];
    BP in24 = (BP)d_in[24];
    BP in25 = (BP)d_in[25];
    BP in26 = (BP)d_in[26];
    BP in27 = (BP)d_in[27];
    BP in28 = (BP)d_in[28];
    BP in29 = (BP)d_in[29];
    BP in30 = (BP)d_in[30];
    BP in31 = (BP)d_in[31];

    float* ws = (float*)d_ws;
    float* trunk   = ws; ws += 560 * L4;
    float* out_fea = ws; ws += CC * L4;
    float* t0      = ws; ws += CC * L4;
    float* xz      = ws; ws += 224 * L4;
    float* xc      = ws; ws += DI * L4;
    float* pk      = ws; ws += 4 * 36 * L4;
    float* delta   = ws; ws += 4 * DI * L4;
    float* ybuf    = ws; ws += 4 * DI * L4;
    float* gbuf    = ws; ws += DI * L4;
    float* ln1buf  = ws; ws += CC * L4;
    float* x_mid   = ws; ws += CC * L4;
    float* xln     = ws; ws += CC * L4;
    float* p1      = ws; ws += 14 * 1024;
    float* p2      = ws; ws += 14 * 256;
    float* p3      = ws; ws += 14 * 64;
    float* s0      = ws; ws += 14 * 4096;
    float* s1      = ws; ws += 14 * 1024;
    float* s2      = ws; ws += 14 * 256;
    float* s3      = ws; ws += 14 * 64;
    float* bufB    = ws; ws += CC * L4;
    float* gB      = ws; ws += CC * L4;
    float* tbuf    = ws; ws += CC * L4;
    float* out_lr  = ws; ws += CC * L4;

    auto nb256 = [](int n) { return dim3((n + 255) / 256); };
    auto gemm_grid = [](int nout) { return dim3(64, (nout + 15) / 16); };

    // stem
    k_fea_pw<<<nb256(CC * L4), 256, 0, stream>>>(in0, in1, t0);
    k_dw3x3<<<nb256(CC * L4), 256, 0, stream>>>(t0, in2, in3, out_fea, CC, HW, 0, nullptr);

    for (int nb = 0; nb < NBLK; ++nb) {
        const float* xin = (nb == 0) ? out_fea : trunk + (size_t)(nb - 1) * CC * L4;
        float* xout = trunk + (size_t)nb * CC * L4;
        BP ln1w = in4 + nb * 56,        ln1b = in5 + nb * 56;
        BP ipw  = in6 + nb * 224 * 56;
        BP cw   = in7 + nb * 112 * 9,   cb   = in8 + nb * 112;
        BP xpw  = in9 + nb * 4 * 36 * 112;
        BP dtw  = in10 + nb * 4 * 112 * 4, dtb = in11 + nb * 448;
        BP alog = in12 + nb * 448 * 16, Dp   = in13 + nb * 448;
        BP onw  = in14 + nb * 112,      onb  = in15 + nb * 112;
        BP opw  = in16 + nb * 56 * 112;
        BP nw   = in17 + nb * 56,       nbv  = in18 + nb * 56;
        BP mw   = in19 + nb * 4 * 14 * 9, mb = in20 + nb * 56;
        BP aw   = in21 + nb * 56 * 56,  ab   = in22 + nb * 56;

        k_ln_pix<<<nb256(L4), 256, 0, stream>>>(xin, ln1w, ln1b, ln1buf, CC, 1e-5f, 0);
        k_gemm<<<gemm_grid(224), 256, 0, stream>>>(ln1buf, ipw, nullptr, nullptr, xz, 56, 224, 0);
        k_dw3x3<<<nb256(DI * L4), 256, 0, stream>>>(xz, cw, cb, xc, DI, HW, 1, nullptr);
        k_gemm<<<gemm_grid(144), 256, 0, stream>>>(xc, xpw, nullptr, nullptr, pk, 112, 144, 1);
        k_delta<<<nb256(4 * DI * L4), 256, 0, stream>>>(pk, dtw, dtb, delta);
        k_scan<<<dim3(4 * DI), 1024, 0, stream>>>(delta, xc, pk, alog, ybuf);
        k_combine<<<nb256(L4), 256, 0, stream>>>(ybuf, xc, xz + 112 * L4, Dp, onw, onb, gbuf);
        k_gemm<<<gemm_grid(56), 256, 0, stream>>>(gbuf, opw, nullptr, xin, x_mid, 112, 56, 0);
        k_ln_pix<<<nb256(L4), 256, 0, stream>>>(x_mid, nw, nbv, xln, CC, 1e-6f, 0);
        k_pools<<<nb256(18816), 256, 0, stream>>>(xln, p1, p2, p3);
        k_mfr<<<nb256(76160), 256, 0, stream>>>(xln, p1, p2, p3, mw, mb, s0, s1, s2, s3);
        k_aggr<<<nb256(CC * L4), 256, 0, stream>>>(s0, s1, s2, s3, xln, x_mid, aw, ab, xout);
    }

    // tail
    k_gemm<<<gemm_grid(56), 256, 0, stream>>>(trunk, in23, in24, nullptr, bufB, 560, 56, 0);
    k_ln_pix<<<nb256(L4), 256, 0, stream>>>(bufB, in25, in26, gB, CC, 1e-6f, 1);
    k_gemm<<<gemm_grid(56), 256, 0, stream>>>(gB, in27, nullptr, nullptr, tbuf, 56, 56, 0);
    k_dw3x3<<<nb256(CC * L4), 256, 0, stream>>>(tbuf, in28, in29, out_lr, CC, HW, 0, out_fea);
    k_up<<<nb256(27 * L4), 256, 0, stream>>>(out_lr, in30, in31, (float*)d_out);
}